// Round 10
// baseline (126.751 us; speedup 1.0000x reference)
//
#include <hip/hip_runtime.h>
#include <hip/hip_fp16.h>

// Unsharp-mask: out = img + param * (img - gaussblur25(img)), param = 5*(tanh(f[b,0])*.5+.5)
// img: (16,3,512,512) fp32. Output: [out (12582912 fp32)] ++ [param (16 fp32)].
//
// Two-phase fused kernel (R10): H-pass reads taps DIRECTLY from global
// (f32, L1/L2-hot; no tileA staging, no unpack cvts) and writes f16 tmpB;
// one barrier; V-pass + epilogue (center re-read from global, exact f32).
// LDS = 12.7 KB -> occupancy wave-capped (8 blocks/CU), not LDS-capped.

#define RADIUS 12
#define KS     25
#define TILE   64
#define PT     (TILE + 2 * RADIUS)   // 88
#define TB_LD  72                    // tmpB f16 stride: 144B/row
#define IMG_W  512
#define IMG_H  512
#define PLANE  (IMG_W * IMG_H)
#define NPLANE 48

// Normalized 25-tap Gaussian, sigma=5
__device__ __constant__ float GW[KS] = {
    0.00453456f, 0.00718308f, 0.01093238f, 0.01598625f, 0.02245983f,
    0.03031760f, 0.03931982f, 0.04899550f, 0.05865827f, 0.06747307f,
    0.07456928f, 0.07918039f, 0.08077993f, 0.07918039f, 0.07456928f,
    0.06747307f, 0.05865827f, 0.04899550f, 0.03931982f, 0.03031760f,
    0.02245983f, 0.01598625f, 0.01093238f, 0.00718308f, 0.00453456f
};

__device__ __forceinline__ int reflect512(int i) {
    i = (i < 0) ? -i : i;
    return (i >= 512) ? (1022 - i) : i;
}

__device__ __forceinline__ float get_elem(const float4& v, int c) {
    return (c == 0) ? v.x : (c == 1) ? v.y : (c == 2) ? v.z : v.w;
}
__device__ __forceinline__ void set_elem(float4& v, int c, float x) {
    if (c == 0) v.x = x; else if (c == 1) v.y = x; else if (c == 2) v.z = x; else v.w = x;
}
__device__ __forceinline__ unsigned h2u(__half2 h) {
    union { __half2 h; unsigned u; } x; x.h = h; return x.u;
}
__device__ __forceinline__ float u_lo(unsigned u) {
    union { unsigned u; __half2 h; } x; x.u = u;
    return __half2float(__low2half(x.h));
}
__device__ __forceinline__ float u_hi(unsigned u) {
    union { unsigned u; __half2 h; } x; x.u = u;
    return __half2float(__high2half(x.h));
}

__global__ __launch_bounds__(256) void usm_fused_kernel(
    const float* __restrict__ img, const float* __restrict__ feat,
    float* __restrict__ out, float* __restrict__ out_param)
{
    __shared__ __half tmpB[PT][TB_LD];   // 88x72 f16 = 12.7 KB

    const int tid = threadIdx.x;
    const int tx0 = blockIdx.x * TILE, ty0 = blockIdx.y * TILE;
    const int zc = blockIdx.z, b = zc / 3;
    const float param = (tanhf(feat[b * 8]) * 0.5f + 0.5f) * 5.0f;
    const float* __restrict__ src = img + (size_t)zc * PLANE;

    // ---- Phase A: horizontal blur, taps from global. 88 rows x 8 slots = 704 units ----
    for (int li = tid; li < PT * (TILE / 8); li += 256) {
        const int py = li >> 3, g = li & 7;
        const int gy = reflect512(ty0 - RADIUS + py);
        const float* __restrict__ rowp = src + (size_t)gy * IMG_W;
        const int gx0 = tx0 + g * 8;          // first output x of this slot

        float4 q[8];                          // taps gx0-12 .. gx0+19
        if (gx0 >= 16 && gx0 <= 488) {
#pragma unroll
            for (int i = 0; i < 8; ++i)
                q[i] = *(const float4*)(rowp + gx0 - 12 + 4 * i);
        } else {
#pragma unroll
            for (int j = 0; j < 32; ++j)
                set_elem(q[j >> 2], j & 3, rowp[reflect512(gx0 - 12 + j)]);
        }

        float acc[8];
#pragma unroll
        for (int o = 0; o < 8; ++o) {
            float a = 0.f;
#pragma unroll
            for (int k = 0; k < KS; ++k) {
                const int idx = o + k;
                a += GW[k] * get_elem(q[idx >> 2], idx & 3);
            }
            acc[o] = a;
        }
        uint4 pk;
        pk.x = h2u(__floats2half2_rn(acc[0], acc[1]));
        pk.y = h2u(__floats2half2_rn(acc[2], acc[3]));
        pk.z = h2u(__floats2half2_rn(acc[4], acc[5]));
        pk.w = h2u(__floats2half2_rn(acc[6], acc[7]));
        *(uint4*)&tmpB[py][g * 8] = pk;
    }
    __syncthreads();

    // ---- Phase B: vertical + epilogue, 4x4 micro-tile per thread (16x16 map) ----
    const int tx4 = (tid & 15) * 4, ry0 = (tid >> 4) * 4;
    float ax[4], ay[4], az[4], aw[4];
#pragma unroll
    for (int d = 0; d < 4; ++d) ax[d] = ay[d] = az[d] = aw[d] = 0.f;

#pragma unroll
    for (int k = 0; k < KS + 3; ++k) {       // 28 b64 row reads
        uint2 rd = *(const uint2*)&tmpB[ry0 + k][tx4];
        const float c0 = u_lo(rd.x), c1 = u_hi(rd.x);
        const float c2 = u_lo(rd.y), c3 = u_hi(rd.y);
#pragma unroll
        for (int d = 0; d < 4; ++d) {
            int kk = k - d;
            if (kk >= 0 && kk < KS) {
                const float wk = GW[kk];
                ax[d] += wk * c0; ay[d] += wk * c1;
                az[d] += wk * c2; aw[d] += wk * c3;
            }
        }
    }

    float* __restrict__ dst = out + (size_t)zc * PLANE;
#pragma unroll
    for (int d = 0; d < 4; ++d) {
        const int oy = ty0 + ry0 + d;
        float4 v = *(const float4*)(src + (size_t)oy * IMG_W + tx0 + tx4);  // exact f32
        float4 o;
        o.x = v.x + param * (v.x - ax[d]);
        o.y = v.y + param * (v.y - ay[d]);
        o.z = v.z + param * (v.z - az[d]);
        o.w = v.w + param * (v.w - aw[d]);
        *(float4*)(dst + (size_t)oy * IMG_W + tx0 + tx4) = o;
    }

    if (tid == 0 && blockIdx.x == 0 && blockIdx.y == 0 && (zc - b * 3) == 0)
        out_param[b] = param;
}

extern "C" void kernel_launch(void* const* d_in, const int* in_sizes, int n_in,
                              void* d_out, int out_size, void* d_ws, size_t ws_size,
                              hipStream_t stream) {
    const float* img  = (const float*)d_in[0];
    const float* feat = (const float*)d_in[1];
    float* out       = (float*)d_out;
    float* out_param = (float*)d_out + (size_t)NPLANE * PLANE;

    usm_fused_kernel<<<dim3(8, 8, NPLANE), 256, 0, stream>>>(img, feat, out, out_param);
}

// Round 11
// 67.399 us; speedup vs baseline: 1.8806x; 1.8806x over previous
//
#include <hip/hip_runtime.h>

// Unsharp-mask: out = img + param * (img - gaussblur25(img)), param = 5*(tanh(f[b,0])*.5+.5)
// img: (16,3,512,512) fp32. Output: [out (12582912 fp32)] ++ [param (16 fp32)].
//
// V-FIRST fused kernel (R10 lesson: horizontal taps from global are
// TA-transaction-bound; vertical taps from global are perfectly coalesced):
//   Phase A: vertical 25-tap conv from GLOBAL (float4, lanes span x),
//            8-row strips with 8 float4 accumulators -> f32 vtmp in LDS.
//   Phase B: horizontal 25-tap conv from LDS + fused epilogue
//            (center re-read from global, exact f32).
// Pure f32 end-to-end. LDS 23.5 KB -> 6 blocks/CU.

#define RADIUS 12
#define KS     25
#define TILE   64
#define PTX    88                    // vtmp cols: tx0-12 .. tx0+75
#define VT_LD  92                    // vtmp row stride (floats), 368B = 23*16B
#define IMG_W  512
#define IMG_H  512
#define PLANE  (IMG_W * IMG_H)
#define NPLANE 48

// Normalized 25-tap Gaussian, sigma=5
__device__ __constant__ float GW[KS] = {
    0.00453456f, 0.00718308f, 0.01093238f, 0.01598625f, 0.02245983f,
    0.03031760f, 0.03931982f, 0.04899550f, 0.05865827f, 0.06747307f,
    0.07456928f, 0.07918039f, 0.08077993f, 0.07918039f, 0.07456928f,
    0.06747307f, 0.05865827f, 0.04899550f, 0.03931982f, 0.03031760f,
    0.02245983f, 0.01598625f, 0.01093238f, 0.00718308f, 0.00453456f
};

__device__ __forceinline__ int reflect512(int i) {
    i = (i < 0) ? -i : i;
    return (i >= 512) ? (1022 - i) : i;
}

__device__ __forceinline__ float get_elem(const float4& v, int c) {
    return (c == 0) ? v.x : (c == 1) ? v.y : (c == 2) ? v.z : v.w;
}

__global__ __launch_bounds__(256) void usm_kernel(
    const float* __restrict__ img, const float* __restrict__ feat,
    float* __restrict__ out, float* __restrict__ out_param)
{
    __shared__ float vtmp[TILE][VT_LD];   // 64 x 92 f32 = 23.5 KB (cols 0..87 used)

    const int tid = threadIdx.x;
    const int tx0 = blockIdx.x * TILE, ty0 = blockIdx.y * TILE;
    const int zc = blockIdx.z, b = zc / 3;
    const float param = (tanhf(feat[b * 8]) * 0.5f + 0.5f) * 5.0f;
    const float* __restrict__ src = img + (size_t)zc * PLANE;

    // ---- Phase A: vertical conv from global. 22 x-slots (float4) x 8 y-strips(8) = 176 units ----
    for (int li = tid; li < 22 * 8; li += 256) {
        const int s     = li % 22;            // lanes 0..21 -> consecutive x (coalesced)
        const int strip = li / 22;
        const int gx    = tx0 - 12 + s * 4;
        const bool xok  = (gx >= 0) && (gx <= IMG_W - 4);
        const int ybase = ty0 + strip * 8 - 12;

        float4 a0, a1, a2, a3, a4, a5, a6, a7;
        a0 = a1 = a2 = a3 = a4 = a5 = a6 = a7 = make_float4(0.f, 0.f, 0.f, 0.f);

#pragma unroll
        for (int j = 0; j < 32; ++j) {        // rows ybase .. ybase+31
            const int gy = reflect512(ybase + j);
            const float* __restrict__ rp = src + (size_t)gy * IMG_W;
            float4 v;
            if (xok) {
                v = *(const float4*)(rp + gx);
            } else {
                v.x = rp[reflect512(gx)];
                v.y = rp[reflect512(gx + 1)];
                v.z = rp[reflect512(gx + 2)];
                v.w = rp[reflect512(gx + 3)];
            }
#pragma unroll
            for (int r = 0; r < 8; ++r) {     // acc[r] += GW[j-r]*v for j-r in [0,24]
                const int k = j - r;
                if (k >= 0 && k < KS) {
                    const float wk = GW[k];
                    float4& a = (r == 0) ? a0 : (r == 1) ? a1 : (r == 2) ? a2 : (r == 3) ? a3
                              : (r == 4) ? a4 : (r == 5) ? a5 : (r == 6) ? a6 : a7;
                    a.x += wk * v.x; a.y += wk * v.y; a.z += wk * v.z; a.w += wk * v.w;
                }
            }
        }
        const int ry = strip * 8;
        *(float4*)&vtmp[ry + 0][s * 4] = a0;
        *(float4*)&vtmp[ry + 1][s * 4] = a1;
        *(float4*)&vtmp[ry + 2][s * 4] = a2;
        *(float4*)&vtmp[ry + 3][s * 4] = a3;
        *(float4*)&vtmp[ry + 4][s * 4] = a4;
        *(float4*)&vtmp[ry + 5][s * 4] = a5;
        *(float4*)&vtmp[ry + 6][s * 4] = a6;
        *(float4*)&vtmp[ry + 7][s * 4] = a7;
    }
    __syncthreads();

    // ---- Phase B: horizontal conv from LDS + epilogue. 16 x-slots x 16 y-groups x 4 rows ----
    const int xs  = tid & 15;                 // output float4 column slot
    const int y0q = (tid >> 4) * 4;           // 4 consecutive output rows
    const int x4  = xs * 4;

    float* __restrict__ dst = out + (size_t)zc * PLANE;
#pragma unroll
    for (int d = 0; d < 4; ++d) {
        const int y = y0q + d;
        float4 q[7];                          // vtmp cols x4 .. x4+27
#pragma unroll
        for (int j = 0; j < 7; ++j)
            q[j] = *(const float4*)&vtmp[y][x4 + 4 * j];

        float4 a = make_float4(0.f, 0.f, 0.f, 0.f);
#pragma unroll
        for (int k = 0; k < KS; ++k) {
            const float wk = GW[k];
            a.x += wk * get_elem(q[(k    ) >> 2], (k    ) & 3);
            a.y += wk * get_elem(q[(k + 1) >> 2], (k + 1) & 3);
            a.z += wk * get_elem(q[(k + 2) >> 2], (k + 2) & 3);
            a.w += wk * get_elem(q[(k + 3) >> 2], (k + 3) & 3);
        }

        const int oy = ty0 + y;
        const float4 v = *(const float4*)(src + (size_t)oy * IMG_W + tx0 + x4);
        float4 o;
        o.x = v.x + param * (v.x - a.x);
        o.y = v.y + param * (v.y - a.y);
        o.z = v.z + param * (v.z - a.z);
        o.w = v.w + param * (v.w - a.w);
        *(float4*)(dst + (size_t)oy * IMG_W + tx0 + x4) = o;
    }

    if (tid == 0 && blockIdx.x == 0 && blockIdx.y == 0 && (zc - b * 3) == 0)
        out_param[b] = param;
}

extern "C" void kernel_launch(void* const* d_in, const int* in_sizes, int n_in,
                              void* d_out, int out_size, void* d_ws, size_t ws_size,
                              hipStream_t stream) {
    const float* img  = (const float*)d_in[0];
    const float* feat = (const float*)d_in[1];
    float* out       = (float*)d_out;
    float* out_param = (float*)d_out + (size_t)NPLANE * PLANE;

    usm_kernel<<<dim3(8, 8, NPLANE), 256, 0, stream>>>(img, feat, out, out_param);
}

// Round 12
// 42.165 us; speedup vs baseline: 3.0060x; 1.5984x over previous
//
#include <hip/hip_runtime.h>
#include <hip/hip_fp16.h>

// Unsharp-mask: out = img + param * (img - gaussblur25(img)), param = 5*(tanh(f[b,0])*.5+.5)
// img: (16,3,512,512) fp32. Output: [out (12582912 fp32)] ++ [param (16 fp32)].
//
// R9 structure (best measured: stage f16 tileA -> H from LDS -> V + epilogue)
// with two upgrades:
//  1) H-phase uses v_dot2_f32_f16: consumes f16 pairs straight from tileA
//     (zero unpack cvts), 2 MACs/inst, f32 accumulate. Odd outputs use
//     v_alignbit-shifted pairs.
//  2) tileA stride 96 -> 104 f16 (208B/row): row bank offsets all-distinct,
//     kills the remaining bank conflicts.

#define RADIUS 12
#define KS     25
#define TILE   64
#define PT     (TILE + 2 * RADIUS)   // 88
#define TA_LD  104                   // tileA f16 stride: 208B/row (16B-aligned)
#define TB_LD  72                    // tmpB  f16 stride: 144B/row
#define IMG_W  512
#define IMG_H  512
#define PLANE  (IMG_W * IMG_H)
#define NPLANE 48

// Normalized 25-tap Gaussian, sigma=5
__device__ __constant__ float GW[KS] = {
    0.00453456f, 0.00718308f, 0.01093238f, 0.01598625f, 0.02245983f,
    0.03031760f, 0.03931982f, 0.04899550f, 0.05865827f, 0.06747307f,
    0.07456928f, 0.07918039f, 0.08077993f, 0.07918039f, 0.07456928f,
    0.06747307f, 0.05865827f, 0.04899550f, 0.03931982f, 0.03031760f,
    0.02245983f, 0.01598625f, 0.01093238f, 0.00718308f, 0.00453456f
};

__device__ __forceinline__ int reflect512(int i) {
    i = (i < 0) ? -i : i;
    return (i >= 512) ? (1022 - i) : i;
}

typedef _Float16 h2_t __attribute__((ext_vector_type(2)));

__device__ __forceinline__ unsigned h2u(__half2 h) {
    union { __half2 h; unsigned u; } x; x.h = h; return x.u;
}
__device__ __forceinline__ float u_lo(unsigned u) {
    union { unsigned u; __half2 h; } x; x.u = u;
    return __half2float(__low2half(x.h));
}
__device__ __forceinline__ float u_hi(unsigned u) {
    union { unsigned u; __half2 h; } x; x.u = u;
    return __half2float(__high2half(x.h));
}

#if __has_builtin(__builtin_amdgcn_fdot2)
#define HAVE_DOT2 1
__device__ __forceinline__ float fdot2u(unsigned a, unsigned b, float c) {
    union { unsigned u; h2_t h; } ua, ub;
    ua.u = a; ub.u = b;
    return __builtin_amdgcn_fdot2(ua.h, ub.h, c, false);
}
#else
#define HAVE_DOT2 0
__device__ __forceinline__ float fdot2u(unsigned a, unsigned b, float c) {
    return c + u_lo(a) * u_lo(b) + u_hi(a) * u_hi(b);
}
#endif

__global__ __launch_bounds__(256) void usm_fused_kernel(
    const float* __restrict__ img, const float* __restrict__ feat,
    float* __restrict__ out, float* __restrict__ out_param)
{
    __shared__ __half tileA[PT][TA_LD];   // 88x104 f16 = 17.9 KB (cols 0..87 used)
    __shared__ __half tmpB[PT][TB_LD];    // 88x72  f16 = 12.4 KB (cols 0..63 used)

    const int tid = threadIdx.x;
    const int tx0 = blockIdx.x * TILE, ty0 = blockIdx.y * TILE;
    const int zc = blockIdx.z, b = zc / 3;
    const float param = (tanhf(feat[b * 8]) * 0.5f + 0.5f) * 5.0f;
    const float* __restrict__ src = img + (size_t)zc * PLANE;
    const bool xedge = (blockIdx.x == 0) || (blockIdx.x == 7);

    // Weight pairs for dot2: W2[m] = (GW[2m], GW[2m+1]); WE=(GW24,0); WO=(0,GW24)
    unsigned W2[12];
#pragma unroll
    for (int m = 0; m < 12; ++m)
        W2[m] = h2u(__floats2half2_rn(GW[2 * m], GW[2 * m + 1]));
    const unsigned WE = h2u(__floats2half2_rn(GW[24], 0.f));
    const unsigned WO = h2u(__floats2half2_rn(0.f, GW[24]));

    // ---- Stage 88x88 padded tile as f16: 88 rows x 11 slots of 8px = 968 ----
    for (int li = tid; li < PT * 11; li += 256) {
        int py = li / 11, s = li - py * 11;
        int gy = reflect512(ty0 - RADIUS + py);
        const float* rowp = src + gy * IMG_W;
        int gx = tx0 - RADIUS + s * 8;
        float4 va, vb;
        if (!xedge) {
            va = *(const float4*)(rowp + gx);
            vb = *(const float4*)(rowp + gx + 4);
        } else {
            va.x = rowp[reflect512(gx)];     va.y = rowp[reflect512(gx + 1)];
            va.z = rowp[reflect512(gx + 2)]; va.w = rowp[reflect512(gx + 3)];
            vb.x = rowp[reflect512(gx + 4)]; vb.y = rowp[reflect512(gx + 5)];
            vb.z = rowp[reflect512(gx + 6)]; vb.w = rowp[reflect512(gx + 7)];
        }
        uint4 pk;
        pk.x = h2u(__floats2half2_rn(va.x, va.y));
        pk.y = h2u(__floats2half2_rn(va.z, va.w));
        pk.z = h2u(__floats2half2_rn(vb.x, vb.y));
        pk.w = h2u(__floats2half2_rn(vb.z, vb.w));
        *(uint4*)&tileA[py][s * 8] = pk;
    }
    __syncthreads();

    // ---- Horizontal via dot2: 88 rows x 8 groups of 8 outputs = 704 slots ----
    for (int li = tid; li < PT * (TILE / 8); li += 256) {
        const int py = li >> 3, g = li & 7;
        const uint4 qa = *(const uint4*)&tileA[py][g * 8];        // P0..P3
        const uint4 qb = *(const uint4*)&tileA[py][g * 8 + 8];    // P4..P7
        const uint4 qc = *(const uint4*)&tileA[py][g * 8 + 16];   // P8..P11
        const uint4 qd = *(const uint4*)&tileA[py][g * 8 + 24];   // P12..P15

        unsigned P[16] = { qa.x, qa.y, qa.z, qa.w, qb.x, qb.y, qb.z, qb.w,
                           qc.x, qc.y, qc.z, qc.w, qd.x, qd.y, qd.z, qd.w };
        unsigned S[15];
#pragma unroll
        for (int i = 0; i < 15; ++i)
            S[i] = __builtin_amdgcn_alignbit(P[i + 1], P[i], 16);

        float acc[8];
#pragma unroll
        for (int h = 0; h < 4; ++h) {          // even outputs o = 2h
            float a = 0.f;
#pragma unroll
            for (int m = 0; m < 12; ++m) a = fdot2u(P[h + m], W2[m], a);
            acc[2 * h] = fdot2u(P[h + 12], WE, a);
        }
#pragma unroll
        for (int h = 0; h < 4; ++h) {          // odd outputs o = 2h+1
            float a = 0.f;
#pragma unroll
            for (int m = 0; m < 12; ++m) a = fdot2u(S[h + m], W2[m], a);
            acc[2 * h + 1] = fdot2u(P[h + 12], WO, a);
        }

        uint4 pk;
        pk.x = h2u(__floats2half2_rn(acc[0], acc[1]));
        pk.y = h2u(__floats2half2_rn(acc[2], acc[3]));
        pk.z = h2u(__floats2half2_rn(acc[4], acc[5]));
        pk.w = h2u(__floats2half2_rn(acc[6], acc[7]));
        *(uint4*)&tmpB[py][g * 8] = pk;
    }
    __syncthreads();

    // ---- Vertical + epilogue: 4x4 micro-tile per thread (16x16 map) ----
    const int tx4 = (tid & 15) * 4, ry0 = (tid >> 4) * 4;
    float ax[4], ay[4], az[4], aw[4];
#pragma unroll
    for (int d = 0; d < 4; ++d) ax[d] = ay[d] = az[d] = aw[d] = 0.f;

#pragma unroll
    for (int k = 0; k < KS + 3; ++k) {       // 28 b64 row reads
        uint2 rd = *(const uint2*)&tmpB[ry0 + k][tx4];
        const float c0 = u_lo(rd.x), c1 = u_hi(rd.x);
        const float c2 = u_lo(rd.y), c3 = u_hi(rd.y);
#pragma unroll
        for (int d = 0; d < 4; ++d) {
            int kk = k - d;
            if (kk >= 0 && kk < KS) {
                const float wk = GW[kk];
                ax[d] += wk * c0; ay[d] += wk * c1;
                az[d] += wk * c2; aw[d] += wk * c3;
            }
        }
    }

    float* __restrict__ dst = out + (size_t)zc * PLANE;
#pragma unroll
    for (int d = 0; d < 4; ++d) {
        const int oy = ty0 + ry0 + d;
        float4 v = *(const float4*)(src + (size_t)oy * IMG_W + tx0 + tx4);  // exact f32
        float4 o;
        o.x = v.x + param * (v.x - ax[d]);
        o.y = v.y + param * (v.y - ay[d]);
        o.z = v.z + param * (v.z - az[d]);
        o.w = v.w + param * (v.w - aw[d]);
        *(float4*)(dst + (size_t)oy * IMG_W + tx0 + tx4) = o;
    }

    if (tid == 0 && blockIdx.x == 0 && blockIdx.y == 0 && (zc - b * 3) == 0)
        out_param[b] = param;
}

extern "C" void kernel_launch(void* const* d_in, const int* in_sizes, int n_in,
                              void* d_out, int out_size, void* d_ws, size_t ws_size,
                              hipStream_t stream) {
    const float* img  = (const float*)d_in[0];
    const float* feat = (const float*)d_in[1];
    float* out       = (float*)d_out;
    float* out_param = (float*)d_out + (size_t)NPLANE * PLANE;

    usm_fused_kernel<<<dim3(8, 8, NPLANE), 256, 0, stream>>>(img, feat, out, out_param);
}